// Round 3
// baseline (1056.202 us; speedup 1.0000x reference)
//
#include <hip/hip_runtime.h>

#define N_NODES 50000
#define N_EDGES 800000
#define DD 128
#define GG 256
#define LL 4
#define EPSV 1e-5f
#define NB 196  // ceil(N_NODES/256)
#define AGG_BLOCKS 3125  // 3125*4 waves = 12500 = N_NODES/4 -> 4 nodes per wave

// ---------------- setup kernels ----------------

__global__ void count_deg_kernel(const int* __restrict__ ei, const float* __restrict__ w,
                                 int* __restrict__ counts, float* __restrict__ deg) {
    int e = blockIdx.x * 256 + threadIdx.x;
    if (e < N_EDGES) {
        int d = ei[N_EDGES + e];
        atomicAdd(&counts[d], 1);
        atomicAdd(&deg[d], w[e]);
    }
}

__global__ void dinv_kernel(const float* __restrict__ deg, float* __restrict__ dinv) {
    int i = blockIdx.x * 256 + threadIdx.x;
    if (i < N_NODES) {
        float d = deg[i] + 2.0f;  // self-loop weight 2.0
        dinv[i] = rsqrtf(fmaxf(d, EPSV));
    }
}

// hierarchical scan, stage 1: per-block (256-node) sums of counts
__global__ __launch_bounds__(256) void blocksum_kernel(const int* __restrict__ counts,
                                                       int* __restrict__ bsums) {
    int i = blockIdx.x * 256 + threadIdx.x;
    int v = (i < N_NODES) ? counts[i] : 0;
    for (int off = 32; off; off >>= 1) v += __shfl_down(v, off);
    __shared__ int s[4];
    if ((threadIdx.x & 63) == 0) s[threadIdx.x >> 6] = v;
    __syncthreads();
    if (threadIdx.x == 0) bsums[blockIdx.x] = s[0] + s[1] + s[2] + s[3];
}

// stage 2: exclusive scan of the 196 block sums (single tiny block)
__global__ __launch_bounds__(256) void scan_bsums_kernel(const int* __restrict__ bsums,
                                                         int* __restrict__ boffs,
                                                         int* __restrict__ rowptr) {
    __shared__ int s[256];
    int t = threadIdx.x;
    int v = (t < NB) ? bsums[t] : 0;
    s[t] = v;
    __syncthreads();
    for (int off = 1; off < 256; off <<= 1) {
        int u = (t >= off) ? s[t - off] : 0;
        __syncthreads();
        s[t] += u;
        __syncthreads();
    }
    if (t < NB) boffs[t] = s[t] - v;  // exclusive
    if (t == 0) rowptr[N_NODES] = N_EDGES;
}

// stage 3: per-block exclusive scan + block offset -> rowptr/cursor
__global__ __launch_bounds__(256) void rowptr_kernel(const int* __restrict__ counts,
                                                     const int* __restrict__ boffs,
                                                     int* __restrict__ rowptr,
                                                     int* __restrict__ cursor) {
    __shared__ int s[256];
    int i = blockIdx.x * 256 + threadIdx.x;
    int t = threadIdx.x;
    int c = (i < N_NODES) ? counts[i] : 0;
    s[t] = c;
    __syncthreads();
    for (int off = 1; off < 256; off <<= 1) {
        int u = (t >= off) ? s[t - off] : 0;
        __syncthreads();
        s[t] += u;
        __syncthreads();
    }
    if (i < N_NODES) {
        int r = boffs[blockIdx.x] + s[t] - c;
        rowptr[i] = r;
        cursor[i] = r;
    }
}

__global__ void fill_kernel(const int* __restrict__ ei, const float* __restrict__ w,
                            const float* __restrict__ dinv, int* __restrict__ cursor,
                            int* __restrict__ srcs, float* __restrict__ norms) {
    int e = blockIdx.x * 256 + threadIdx.x;
    if (e < N_EDGES) {
        int s_ = ei[e];
        int d = ei[N_EDGES + e];
        int pos = atomicAdd(&cursor[d], 1);
        srcs[pos] = s_;
        norms[pos] = dinv[s_] * w[e] * dinv[d];
    }
}

// ---------------- GEMM: out[n,128] = act(A)[n,128] @ W[128,128] (+bias) ----------------
// act = affine(g,beta)+relu if AFFINE.  STATS: accumulate col sum/sumsq of out.

template <bool AFFINE, bool STATS, bool BIAS>
__global__ __launch_bounds__(256) void gemm128(const float* __restrict__ A, int n,
                                               const float* __restrict__ W,
                                               const float* __restrict__ bias,
                                               const float* __restrict__ aff,
                                               float* __restrict__ out,
                                               float* __restrict__ stats) {
    __shared__ float As[128][64];  // As[k][r] (transposed)
    __shared__ float Ws[128][64];  // Ws[k][c]
    int tid = threadIdx.x;
    int row0 = blockIdx.y * 64;
    int col0 = blockIdx.x * 64;

    {   // load + transform A tile
        int rsub = tid >> 5;         // 0..7
        int k4 = (tid & 31) * 4;     // 0..124
        for (int it = 0; it < 8; ++it) {
            int r = it * 8 + rsub;
            int row = row0 + r;
            float4 v = make_float4(0.f, 0.f, 0.f, 0.f);
            if (row < n) v = *(const float4*)&A[(size_t)row * 128 + k4];
            if (AFFINE) {
                float4 g = *(const float4*)&aff[k4];
                float4 bb = *(const float4*)&aff[128 + k4];
                v.x = fmaxf(v.x * g.x + bb.x, 0.f);
                v.y = fmaxf(v.y * g.y + bb.y, 0.f);
                v.z = fmaxf(v.z * g.z + bb.z, 0.f);
                v.w = fmaxf(v.w * g.w + bb.w, 0.f);
            }
            As[k4 + 0][r] = v.x;
            As[k4 + 1][r] = v.y;
            As[k4 + 2][r] = v.z;
            As[k4 + 3][r] = v.w;
        }
    }
    {   // load W tile
        int krow = tid >> 4;          // 0..15
        int c4 = (tid & 15) * 4;      // 0..60
        for (int it = 0; it < 8; ++it) {
            int k = it * 16 + krow;
            *(float4*)&Ws[k][c4] = *(const float4*)&W[k * 128 + col0 + c4];
        }
    }
    __syncthreads();

    int ty = tid >> 4, tx = tid & 15;
    float acc[4][4];
#pragma unroll
    for (int i = 0; i < 4; i++)
#pragma unroll
        for (int j = 0; j < 4; j++) acc[i][j] = 0.f;

#pragma unroll 4
    for (int k = 0; k < 128; k++) {
        float4 a = *(const float4*)&As[k][ty * 4];
        float4 b = *(const float4*)&Ws[k][tx * 4];
        float av[4] = {a.x, a.y, a.z, a.w};
        float bv[4] = {b.x, b.y, b.z, b.w};
#pragma unroll
        for (int i = 0; i < 4; i++)
#pragma unroll
            for (int j = 0; j < 4; j++) acc[i][j] += av[i] * bv[j];
    }

    float csum[4] = {0, 0, 0, 0}, csq[4] = {0, 0, 0, 0};
#pragma unroll
    for (int i = 0; i < 4; i++) {
        int row = row0 + ty * 4 + i;
        if (row < n) {
#pragma unroll
            for (int j = 0; j < 4; j++) {
                float v = acc[i][j];
                if (BIAS) v += bias[col0 + tx * 4 + j];
                out[(size_t)row * 128 + col0 + tx * 4 + j] = v;
                if (STATS) {
                    csum[j] += v;
                    csq[j] += v * v;
                }
            }
        }
    }
    if (STATS) {
        // reuse As storage for the 128-float partial buffers
        float* ps = &As[0][0];
        float* pq = &As[0][0] + 64;
        __syncthreads();
        if (tid < 64) { ps[tid] = 0.f; pq[tid] = 0.f; }
        __syncthreads();
#pragma unroll
        for (int j = 0; j < 4; j++) {
            atomicAdd(&ps[tx * 4 + j], csum[j]);
            atomicAdd(&pq[tx * 4 + j], csq[j]);
        }
        __syncthreads();
        if (tid < 64) {
            atomicAdd(&stats[col0 + tid], ps[tid]);
            atomicAdd(&stats[128 + col0 + tid], pq[tid]);
        }
    }
}

// ---------------- BN affine param kernel ----------------
__global__ void affine_kernel(const float* __restrict__ stats, const float* __restrict__ s,
                              const float* __restrict__ b, float* __restrict__ aff, float invN) {
    int i = threadIdx.x;  // 128
    float mean = stats[i] * invN;
    float var = fmaxf(stats[128 + i] * invN - mean * mean, 0.f);
    float g = s[i] * rsqrtf(var + EPSV);
    aff[i] = g;
    aff[128 + i] = b[i] - mean * g;
}

// ---------------- aggregation: out[i] = sum_e norm*hT[src] + selfnorm*hT[i] + convb ----------------
// one wave per node (lane = 2 features); 12500 waves -> 4 nodes/wave; edge loop unrolled x4
__global__ __launch_bounds__(256) void agg_kernel(const float* __restrict__ hT,
                                                  const int* __restrict__ rowptr,
                                                  const int* __restrict__ srcs,
                                                  const float* __restrict__ norms,
                                                  const float* __restrict__ dinv,
                                                  const float* __restrict__ convb,
                                                  float* __restrict__ out,
                                                  float* __restrict__ stats) {
    __shared__ float ps[4][256];
    int wave = threadIdx.x >> 6, lane = threadIdx.x & 63;
    int d0 = lane * 2;
    float2 bb = *(const float2*)&convb[d0];
    float sum0 = 0, sum1 = 0, sq0 = 0, sq1 = 0;
    for (int i = blockIdx.x * 4 + wave; i < N_NODES; i += AGG_BLOCKS * 4) {
        float di = dinv[i];
        float sn = 2.0f * di * di;
        float2 hv = *(const float2*)&hT[(size_t)i * 128 + d0];
        float ax = sn * hv.x, ay = sn * hv.y;
        int beg = rowptr[i], end = rowptr[i + 1];
        int e = beg;
        for (; e + 3 < end; e += 4) {
            int s0 = srcs[e], s1 = srcs[e + 1], s2 = srcs[e + 2], s3 = srcs[e + 3];
            float n0 = norms[e], n1 = norms[e + 1], n2 = norms[e + 2], n3 = norms[e + 3];
            float2 h0 = *(const float2*)&hT[(size_t)s0 * 128 + d0];
            float2 h1 = *(const float2*)&hT[(size_t)s1 * 128 + d0];
            float2 h2 = *(const float2*)&hT[(size_t)s2 * 128 + d0];
            float2 h3 = *(const float2*)&hT[(size_t)s3 * 128 + d0];
            ax += n0 * h0.x + n1 * h1.x + n2 * h2.x + n3 * h3.x;
            ay += n0 * h0.y + n1 * h1.y + n2 * h2.y + n3 * h3.y;
        }
        for (; e < end; ++e) {
            int s0 = srcs[e];
            float n0 = norms[e];
            float2 h0 = *(const float2*)&hT[(size_t)s0 * 128 + d0];
            ax += n0 * h0.x;
            ay += n0 * h0.y;
        }
        float ox = ax + bb.x, oy = ay + bb.y;
        *(float2*)&out[(size_t)i * 128 + d0] = make_float2(ox, oy);
        sum0 += ox; sum1 += oy;
        sq0 += ox * ox; sq1 += oy * oy;
    }
    ps[wave][d0] = sum0;
    ps[wave][d0 + 1] = sum1;
    ps[wave][128 + d0] = sq0;
    ps[wave][128 + d0 + 1] = sq1;
    __syncthreads();
    int t = threadIdx.x;
    float v = ps[0][t] + ps[1][t] + ps[2][t] + ps[3][t];
    atomicAdd(&stats[t], v);
}

// ---------------- pooling (batch is sorted) ----------------
__global__ __launch_bounds__(256) void pool_kernel(const float* __restrict__ h,
                                                   const float* __restrict__ aff,
                                                   const int* __restrict__ batch,
                                                   float* __restrict__ pooled,
                                                   float* __restrict__ cnt) {
    int base = blockIdx.x * 256;
    if (base >= N_NODES) return;
    int last = min(base + 255, N_NODES - 1);
    int bmin = batch[base], bmax = batch[last];
    int wave = threadIdx.x >> 6, lane = threadIdx.x & 63;
    int d0 = lane * 2;
    __shared__ float acc[4][128];
    __shared__ int ccnt[4];
    float ga0 = aff[d0], ga1 = aff[d0 + 1];
    float gb0 = aff[128 + d0], gb1 = aff[128 + d0 + 1];
    for (int g = bmin; g <= bmax; ++g) {
        float ax = 0.f, ay = 0.f;
        int local = 0;
        for (int j = wave; j < 256; j += 4) {
            int i = base + j;
            if (i < N_NODES && batch[i] == g) {
                float2 hv = *(const float2*)&h[(size_t)i * 128 + d0];
                ax += fmaxf(hv.x * ga0 + gb0, 0.f);
                ay += fmaxf(hv.y * ga1 + gb1, 0.f);
                local++;
            }
        }
        acc[wave][d0] = ax;
        acc[wave][d0 + 1] = ay;
        if (lane == 0) ccnt[wave] = local;
        __syncthreads();
        if (threadIdx.x < 128) {
            float t = acc[0][threadIdx.x] + acc[1][threadIdx.x] + acc[2][threadIdx.x] +
                      acc[3][threadIdx.x];
            atomicAdd(&pooled[g * 128 + threadIdx.x], t);
        } else if (threadIdx.x == 128) {
            atomicAdd(&cnt[g], (float)(ccnt[0] + ccnt[1] + ccnt[2] + ccnt[3]));
        }
        __syncthreads();
    }
}

__global__ void pooldiv_kernel(float* __restrict__ pooled, const float* __restrict__ cnt) {
    int idx = blockIdx.x * 256 + threadIdx.x;
    if (idx < GG * 128) {
        int g = idx >> 7;
        pooled[idx] *= 1.0f / fmaxf(cnt[g], 1.0f);
    }
}

// ---------------- output head ----------------
__global__ void out_kernel(const float* __restrict__ Z, const float* __restrict__ aff,
                           const float* __restrict__ outW, const float* __restrict__ outb,
                           float* __restrict__ out) {
    int g = blockIdx.x;
    int lane = threadIdx.x;  // 64
    int d0 = lane * 2;
    float2 z = *(const float2*)&Z[(size_t)g * 128 + d0];
    float s = fmaxf(z.x * aff[d0] + aff[128 + d0], 0.f) * outW[d0] +
              fmaxf(z.y * aff[d0 + 1] + aff[128 + d0 + 1], 0.f) * outW[d0 + 1];
    for (int off = 32; off; off >>= 1) s += __shfl_down(s, off);
    if (lane == 0) out[g] = s + outb[0];
}

// ---------------- host ----------------
extern "C" void kernel_launch(void* const* d_in, const int* in_sizes, int n_in,
                              void* d_out, int out_size, void* d_ws, size_t ws_size,
                              hipStream_t stream) {
    const float* x         = (const float*)d_in[0];
    const int*   ei        = (const int*)d_in[1];
    const float* ew        = (const float*)d_in[2];
    const int*   batch     = (const int*)d_in[3];
    const float* pre_W     = (const float*)d_in[4];
    const float* pre_b     = (const float*)d_in[5];
    const float* pre_bn_s  = (const float*)d_in[6];
    const float* pre_bn_b  = (const float*)d_in[7];
    const float* convW     = (const float*)d_in[8];
    const float* convb     = (const float*)d_in[9];
    const float* bn_s      = (const float*)d_in[10];
    const float* bn_b      = (const float*)d_in[11];
    const float* post_W    = (const float*)d_in[12];
    const float* post_b    = (const float*)d_in[13];
    const float* post_bn_s = (const float*)d_in[14];
    const float* post_bn_b = (const float*)d_in[15];
    const float* out_W     = (const float*)d_in[16];
    const float* out_b     = (const float*)d_in[17];

    float* ws = (float*)d_ws;
    float* deg    = ws;                        // N
    int*   counts = (int*)(ws + N_NODES);      // N
    float* stats  = ws + 2 * N_NODES;          // 6*256
    float* pooled = stats + 6 * 256;           // 256*128
    float* cnt    = pooled + GG * 128;         // 256
    size_t zero_floats = 2 * N_NODES + 6 * 256 + GG * 128 + GG;
    float* Z      = cnt + GG;                  // 256*128
    float* aff    = Z + GG * 128;              // 6*256
    int*   rowptr = (int*)(aff + 6 * 256);     // N+1
    int*   cursor = rowptr + N_NODES + 1;      // N
    int*   bsums  = cursor + N_NODES;          // NB
    int*   boffs  = bsums + NB;                // NB
    int*   srcs   = boffs + NB;                // E
    float* norms  = (float*)(srcs + N_EDGES);  // E
    float* dinv   = norms + N_EDGES;           // N
    size_t off = (size_t)(dinv + N_NODES - ws);
    off = (off + 3) & ~(size_t)3;              // 16B align
    float* hA = ws + off;                      // N*128
    float* hB = hA + (size_t)N_NODES * 128;    // N*128

    hipMemsetAsync(d_ws, 0, zero_floats * sizeof(float), stream);
    count_deg_kernel<<<(N_EDGES + 255) / 256, 256, 0, stream>>>(ei, ew, counts, deg);
    dinv_kernel<<<(N_NODES + 255) / 256, 256, 0, stream>>>(deg, dinv);
    blocksum_kernel<<<NB, 256, 0, stream>>>(counts, bsums);
    scan_bsums_kernel<<<1, 256, 0, stream>>>(bsums, boffs, rowptr);
    rowptr_kernel<<<NB, 256, 0, stream>>>(counts, boffs, rowptr, cursor);
    fill_kernel<<<(N_EDGES + 255) / 256, 256, 0, stream>>>(ei, ew, dinv, cursor, srcs, norms);

    dim3 gN(2, (N_NODES + 63) / 64);
    // pre FC: hA = x @ pre_W + pre_b, stats0
    gemm128<false, true, true><<<gN, 256, 0, stream>>>(x, N_NODES, pre_W, pre_b, nullptr, hA,
                                                       stats + 0);
    affine_kernel<<<1, 128, 0, stream>>>(stats + 0, pre_bn_s, pre_bn_b, aff + 0,
                                         1.0f / N_NODES);
    for (int l = 0; l < LL; l++) {
        // hB = relu(bn(hA)) @ convW[l]
        gemm128<true, false, false><<<gN, 256, 0, stream>>>(hA, N_NODES, convW + l * 128 * 128,
                                                            nullptr, aff + l * 256, hB, nullptr);
        // hA = scatter(hB) + convb[l], stats_{l+1}
        agg_kernel<<<AGG_BLOCKS, 256, 0, stream>>>(hB, rowptr, srcs, norms, dinv,
                                                   convb + l * 128, hA,
                                                   stats + (l + 1) * 256);
        affine_kernel<<<1, 128, 0, stream>>>(stats + (l + 1) * 256, bn_s + l * 128,
                                             bn_b + l * 128, aff + (l + 1) * 256,
                                             1.0f / N_NODES);
    }
    // mean pool of relu(bn(hA))
    pool_kernel<<<(N_NODES + 255) / 256, 256, 0, stream>>>(hA, aff + 4 * 256, batch, pooled, cnt);
    pooldiv_kernel<<<(GG * 128 + 255) / 256, 256, 0, stream>>>(pooled, cnt);
    // post FC
    dim3 gP(2, 4);
    gemm128<false, true, true><<<gP, 256, 0, stream>>>(pooled, GG, post_W, post_b, nullptr, Z,
                                                       stats + 5 * 256);
    affine_kernel<<<1, 128, 0, stream>>>(stats + 5 * 256, post_bn_s, post_bn_b, aff + 5 * 256,
                                         1.0f / GG);
    out_kernel<<<GG, 64, 0, stream>>>(Z, aff + 5 * 256, out_W, out_b, (float*)d_out);
}

// Round 4
// 888.026 us; speedup vs baseline: 1.1894x; 1.1894x over previous
//
#include <hip/hip_runtime.h>

#define N_NODES 50000
#define N_EDGES 800000
#define DD 128
#define GG 256
#define LL 4
#define EPSV 1e-5f
#define NB 196  // ceil(N_NODES/256)
#define AGG_BLOCKS 1024  // R2's best: more waves REGRESSED (R3: 3125 blocks -> BW down 11%)

// ---------------- bf16 helpers ----------------
static __device__ __forceinline__ unsigned bf16pack(float a, float b) {
    unsigned ua = __float_as_uint(a), ub = __float_as_uint(b);
    ua = (ua + 0x7FFFu + ((ua >> 16) & 1u)) >> 16;     // RNE
    ub = (ub + 0x7FFFu + ((ub >> 16) & 1u)) >> 16;
    return ua | (ub << 16);
}
static __device__ __forceinline__ float2 bf16unpack(unsigned u) {
    float2 r;
    r.x = __uint_as_float(u << 16);
    r.y = __uint_as_float(u & 0xFFFF0000u);
    return r;
}

// ---------------- setup kernels ----------------

__global__ void count_deg_kernel(const int* __restrict__ ei, const float* __restrict__ w,
                                 int* __restrict__ counts, float* __restrict__ deg) {
    int e = blockIdx.x * 256 + threadIdx.x;
    if (e < N_EDGES) {
        int d = ei[N_EDGES + e];
        atomicAdd(&counts[d], 1);
        atomicAdd(&deg[d], w[e]);
    }
}

__global__ void dinv_kernel(const float* __restrict__ deg, float* __restrict__ dinv) {
    int i = blockIdx.x * 256 + threadIdx.x;
    if (i < N_NODES) {
        float d = deg[i] + 2.0f;  // self-loop weight 2.0
        dinv[i] = rsqrtf(fmaxf(d, EPSV));
    }
}

// hierarchical scan, stage 1: per-block (256-node) sums of counts
__global__ __launch_bounds__(256) void blocksum_kernel(const int* __restrict__ counts,
                                                       int* __restrict__ bsums) {
    int i = blockIdx.x * 256 + threadIdx.x;
    int v = (i < N_NODES) ? counts[i] : 0;
    for (int off = 32; off; off >>= 1) v += __shfl_down(v, off);
    __shared__ int s[4];
    if ((threadIdx.x & 63) == 0) s[threadIdx.x >> 6] = v;
    __syncthreads();
    if (threadIdx.x == 0) bsums[blockIdx.x] = s[0] + s[1] + s[2] + s[3];
}

// stage 2: exclusive scan of the 196 block sums (single tiny block)
__global__ __launch_bounds__(256) void scan_bsums_kernel(const int* __restrict__ bsums,
                                                         int* __restrict__ boffs,
                                                         int* __restrict__ rowptr) {
    __shared__ int s[256];
    int t = threadIdx.x;
    int v = (t < NB) ? bsums[t] : 0;
    s[t] = v;
    __syncthreads();
    for (int off = 1; off < 256; off <<= 1) {
        int u = (t >= off) ? s[t - off] : 0;
        __syncthreads();
        s[t] += u;
        __syncthreads();
    }
    if (t < NB) boffs[t] = s[t] - v;  // exclusive
    if (t == 0) rowptr[N_NODES] = N_EDGES;
}

// stage 3: per-block exclusive scan + block offset -> rowptr/cursor
__global__ __launch_bounds__(256) void rowptr_kernel(const int* __restrict__ counts,
                                                     const int* __restrict__ boffs,
                                                     int* __restrict__ rowptr,
                                                     int* __restrict__ cursor) {
    __shared__ int s[256];
    int i = blockIdx.x * 256 + threadIdx.x;
    int t = threadIdx.x;
    int c = (i < N_NODES) ? counts[i] : 0;
    s[t] = c;
    __syncthreads();
    for (int off = 1; off < 256; off <<= 1) {
        int u = (t >= off) ? s[t - off] : 0;
        __syncthreads();
        s[t] += u;
        __syncthreads();
    }
    if (i < N_NODES) {
        int r = boffs[blockIdx.x] + s[t] - c;
        rowptr[i] = r;
        cursor[i] = r;
    }
}

__global__ void fill_kernel(const int* __restrict__ ei, const float* __restrict__ w,
                            const float* __restrict__ dinv, int* __restrict__ cursor,
                            int* __restrict__ srcs, float* __restrict__ norms) {
    int e = blockIdx.x * 256 + threadIdx.x;
    if (e < N_EDGES) {
        int s_ = ei[e];
        int d = ei[N_EDGES + e];
        int pos = atomicAdd(&cursor[d], 1);
        srcs[pos] = s_;
        norms[pos] = dinv[s_] * w[e] * dinv[d];
    }
}

// ---------------- GEMM: out[n,128] = act(A)[n,128] @ W[128,128] (+bias) ----------------
// act = affine(g,beta)+relu if AFFINE.  STATS: col sum/sumsq.  OUTBF16: write packed bf16 pairs.

template <bool AFFINE, bool STATS, bool BIAS, bool OUTBF16>
__global__ __launch_bounds__(256) void gemm128(const float* __restrict__ A, int n,
                                               const float* __restrict__ W,
                                               const float* __restrict__ bias,
                                               const float* __restrict__ aff,
                                               void* __restrict__ outv,
                                               float* __restrict__ stats) {
    __shared__ float As[128][64];  // As[k][r] (transposed)
    __shared__ float Ws[128][64];  // Ws[k][c]
    int tid = threadIdx.x;
    int row0 = blockIdx.y * 64;
    int col0 = blockIdx.x * 64;

    {   // load + transform A tile
        int rsub = tid >> 5;         // 0..7
        int k4 = (tid & 31) * 4;     // 0..124
        for (int it = 0; it < 8; ++it) {
            int r = it * 8 + rsub;
            int row = row0 + r;
            float4 v = make_float4(0.f, 0.f, 0.f, 0.f);
            if (row < n) v = *(const float4*)&A[(size_t)row * 128 + k4];
            if (AFFINE) {
                float4 g = *(const float4*)&aff[k4];
                float4 bb = *(const float4*)&aff[128 + k4];
                v.x = fmaxf(v.x * g.x + bb.x, 0.f);
                v.y = fmaxf(v.y * g.y + bb.y, 0.f);
                v.z = fmaxf(v.z * g.z + bb.z, 0.f);
                v.w = fmaxf(v.w * g.w + bb.w, 0.f);
            }
            As[k4 + 0][r] = v.x;
            As[k4 + 1][r] = v.y;
            As[k4 + 2][r] = v.z;
            As[k4 + 3][r] = v.w;
        }
    }
    {   // load W tile
        int krow = tid >> 4;          // 0..15
        int c4 = (tid & 15) * 4;      // 0..60
        for (int it = 0; it < 8; ++it) {
            int k = it * 16 + krow;
            *(float4*)&Ws[k][c4] = *(const float4*)&W[k * 128 + col0 + c4];
        }
    }
    __syncthreads();

    int ty = tid >> 4, tx = tid & 15;
    float acc[4][4];
#pragma unroll
    for (int i = 0; i < 4; i++)
#pragma unroll
        for (int j = 0; j < 4; j++) acc[i][j] = 0.f;

#pragma unroll 4
    for (int k = 0; k < 128; k++) {
        float4 a = *(const float4*)&As[k][ty * 4];
        float4 b = *(const float4*)&Ws[k][tx * 4];
        float av[4] = {a.x, a.y, a.z, a.w};
        float bv[4] = {b.x, b.y, b.z, b.w};
#pragma unroll
        for (int i = 0; i < 4; i++)
#pragma unroll
            for (int j = 0; j < 4; j++) acc[i][j] += av[i] * bv[j];
    }

    float csum[4] = {0, 0, 0, 0}, csq[4] = {0, 0, 0, 0};
#pragma unroll
    for (int i = 0; i < 4; i++) {
        int row = row0 + ty * 4 + i;
        if (row < n) {
            int c = col0 + tx * 4;
            if (OUTBF16) {
                uint2 p;
                p.x = bf16pack(acc[i][0], acc[i][1]);
                p.y = bf16pack(acc[i][2], acc[i][3]);
                *(uint2*)&((unsigned*)outv)[((size_t)row * 128 + c) >> 1] = p;
            } else {
#pragma unroll
                for (int j = 0; j < 4; j++) {
                    float v = acc[i][j];
                    if (BIAS) v += bias[c + j];
                    ((float*)outv)[(size_t)row * 128 + c + j] = v;
                    if (STATS) {
                        csum[j] += v;
                        csq[j] += v * v;
                    }
                }
            }
        }
    }
    if (STATS) {
        // reuse As storage for the 128-float partial buffers
        float* ps = &As[0][0];
        float* pq = &As[0][0] + 64;
        __syncthreads();
        if (tid < 64) { ps[tid] = 0.f; pq[tid] = 0.f; }
        __syncthreads();
#pragma unroll
        for (int j = 0; j < 4; j++) {
            atomicAdd(&ps[tx * 4 + j], csum[j]);
            atomicAdd(&pq[tx * 4 + j], csq[j]);
        }
        __syncthreads();
        if (tid < 64) {
            atomicAdd(&stats[col0 + tid], ps[tid]);
            atomicAdd(&stats[128 + col0 + tid], pq[tid]);
        }
    }
}

// ---------------- BN affine param kernel ----------------
__global__ void affine_kernel(const float* __restrict__ stats, const float* __restrict__ s,
                              const float* __restrict__ b, float* __restrict__ aff, float invN) {
    int i = threadIdx.x;  // 128
    float mean = stats[i] * invN;
    float var = fmaxf(stats[128 + i] * invN - mean * mean, 0.f);
    float g = s[i] * rsqrtf(var + EPSV);
    aff[i] = g;
    aff[128 + i] = b[i] - mean * g;
}

// ---------------- aggregation: out[i] = sum_e norm*h[src] + selfnorm*h[i] + convb ----------------
// h rows are packed bf16 pairs (64 uints/row); accumulate fp32; one wave per node.
__global__ __launch_bounds__(256) void agg_kernel(const unsigned* __restrict__ hT,
                                                  const int* __restrict__ rowptr,
                                                  const int* __restrict__ srcs,
                                                  const float* __restrict__ norms,
                                                  const float* __restrict__ dinv,
                                                  const float* __restrict__ convb,
                                                  float* __restrict__ out,
                                                  float* __restrict__ stats) {
    __shared__ float ps[4][256];
    int wave = threadIdx.x >> 6, lane = threadIdx.x & 63;
    int d0 = lane * 2;
    float2 bb = *(const float2*)&convb[d0];
    float sum0 = 0, sum1 = 0, sq0 = 0, sq1 = 0;
    for (int i = blockIdx.x * 4 + wave; i < N_NODES; i += AGG_BLOCKS * 4) {
        float di = dinv[i];
        float sn = 2.0f * di * di;
        float2 hv = bf16unpack(hT[(size_t)i * 64 + lane]);
        float ax = sn * hv.x, ay = sn * hv.y;
        int beg = rowptr[i], end = rowptr[i + 1];
        int e = beg;
        for (; e + 3 < end; e += 4) {
            int s0 = srcs[e], s1 = srcs[e + 1], s2 = srcs[e + 2], s3 = srcs[e + 3];
            float n0 = norms[e], n1 = norms[e + 1], n2 = norms[e + 2], n3 = norms[e + 3];
            float2 h0 = bf16unpack(hT[(size_t)s0 * 64 + lane]);
            float2 h1 = bf16unpack(hT[(size_t)s1 * 64 + lane]);
            float2 h2 = bf16unpack(hT[(size_t)s2 * 64 + lane]);
            float2 h3 = bf16unpack(hT[(size_t)s3 * 64 + lane]);
            ax += n0 * h0.x + n1 * h1.x + n2 * h2.x + n3 * h3.x;
            ay += n0 * h0.y + n1 * h1.y + n2 * h2.y + n3 * h3.y;
        }
        for (; e < end; ++e) {
            int s0 = srcs[e];
            float n0 = norms[e];
            float2 h0 = bf16unpack(hT[(size_t)s0 * 64 + lane]);
            ax += n0 * h0.x;
            ay += n0 * h0.y;
        }
        float ox = ax + bb.x, oy = ay + bb.y;
        *(float2*)&out[(size_t)i * 128 + d0] = make_float2(ox, oy);
        sum0 += ox; sum1 += oy;
        sq0 += ox * ox; sq1 += oy * oy;
    }
    ps[wave][d0] = sum0;
    ps[wave][d0 + 1] = sum1;
    ps[wave][128 + d0] = sq0;
    ps[wave][128 + d0 + 1] = sq1;
    __syncthreads();
    int t = threadIdx.x;
    float v = ps[0][t] + ps[1][t] + ps[2][t] + ps[3][t];
    atomicAdd(&stats[t], v);
}

// ---------------- pooling (batch is sorted) ----------------
__global__ __launch_bounds__(256) void pool_kernel(const float* __restrict__ h,
                                                   const float* __restrict__ aff,
                                                   const int* __restrict__ batch,
                                                   float* __restrict__ pooled,
                                                   float* __restrict__ cnt) {
    int base = blockIdx.x * 256;
    if (base >= N_NODES) return;
    int last = min(base + 255, N_NODES - 1);
    int bmin = batch[base], bmax = batch[last];
    int wave = threadIdx.x >> 6, lane = threadIdx.x & 63;
    int d0 = lane * 2;
    __shared__ float acc[4][128];
    __shared__ int ccnt[4];
    float ga0 = aff[d0], ga1 = aff[d0 + 1];
    float gb0 = aff[128 + d0], gb1 = aff[128 + d0 + 1];
    for (int g = bmin; g <= bmax; ++g) {
        float ax = 0.f, ay = 0.f;
        int local = 0;
        for (int j = wave; j < 256; j += 4) {
            int i = base + j;
            if (i < N_NODES && batch[i] == g) {
                float2 hv = *(const float2*)&h[(size_t)i * 128 + d0];
                ax += fmaxf(hv.x * ga0 + gb0, 0.f);
                ay += fmaxf(hv.y * ga1 + gb1, 0.f);
                local++;
            }
        }
        acc[wave][d0] = ax;
        acc[wave][d0 + 1] = ay;
        if (lane == 0) ccnt[wave] = local;
        __syncthreads();
        if (threadIdx.x < 128) {
            float t = acc[0][threadIdx.x] + acc[1][threadIdx.x] + acc[2][threadIdx.x] +
                      acc[3][threadIdx.x];
            atomicAdd(&pooled[g * 128 + threadIdx.x], t);
        } else if (threadIdx.x == 128) {
            atomicAdd(&cnt[g], (float)(ccnt[0] + ccnt[1] + ccnt[2] + ccnt[3]));
        }
        __syncthreads();
    }
}

__global__ void pooldiv_kernel(float* __restrict__ pooled, const float* __restrict__ cnt) {
    int idx = blockIdx.x * 256 + threadIdx.x;
    if (idx < GG * 128) {
        int g = idx >> 7;
        pooled[idx] *= 1.0f / fmaxf(cnt[g], 1.0f);
    }
}

// ---------------- output head ----------------
__global__ void out_kernel(const float* __restrict__ Z, const float* __restrict__ aff,
                           const float* __restrict__ outW, const float* __restrict__ outb,
                           float* __restrict__ out) {
    int g = blockIdx.x;
    int lane = threadIdx.x;  // 64
    int d0 = lane * 2;
    float2 z = *(const float2*)&Z[(size_t)g * 128 + d0];
    float s = fmaxf(z.x * aff[d0] + aff[128 + d0], 0.f) * outW[d0] +
              fmaxf(z.y * aff[d0 + 1] + aff[128 + d0 + 1], 0.f) * outW[d0 + 1];
    for (int off = 32; off; off >>= 1) s += __shfl_down(s, off);
    if (lane == 0) out[g] = s + outb[0];
}

// ---------------- host ----------------
extern "C" void kernel_launch(void* const* d_in, const int* in_sizes, int n_in,
                              void* d_out, int out_size, void* d_ws, size_t ws_size,
                              hipStream_t stream) {
    const float* x         = (const float*)d_in[0];
    const int*   ei        = (const int*)d_in[1];
    const float* ew        = (const float*)d_in[2];
    const int*   batch     = (const int*)d_in[3];
    const float* pre_W     = (const float*)d_in[4];
    const float* pre_b     = (const float*)d_in[5];
    const float* pre_bn_s  = (const float*)d_in[6];
    const float* pre_bn_b  = (const float*)d_in[7];
    const float* convW     = (const float*)d_in[8];
    const float* convb     = (const float*)d_in[9];
    const float* bn_s      = (const float*)d_in[10];
    const float* bn_b      = (const float*)d_in[11];
    const float* post_W    = (const float*)d_in[12];
    const float* post_b    = (const float*)d_in[13];
    const float* post_bn_s = (const float*)d_in[14];
    const float* post_bn_b = (const float*)d_in[15];
    const float* out_W     = (const float*)d_in[16];
    const float* out_b     = (const float*)d_in[17];

    float* ws = (float*)d_ws;
    float* deg    = ws;                        // N
    int*   counts = (int*)(ws + N_NODES);      // N
    float* stats  = ws + 2 * N_NODES;          // 6*256
    float* pooled = stats + 6 * 256;           // 256*128
    float* cnt    = pooled + GG * 128;         // 256
    size_t zero_floats = 2 * N_NODES + 6 * 256 + GG * 128 + GG;
    float* Z      = cnt + GG;                  // 256*128
    float* aff    = Z + GG * 128;              // 6*256
    int*   rowptr = (int*)(aff + 6 * 256);     // N+1
    int*   cursor = rowptr + N_NODES + 1;      // N
    int*   bsums  = cursor + N_NODES;          // NB
    int*   boffs  = bsums + NB;                // NB
    int*   srcs   = boffs + NB;                // E
    float* norms  = (float*)(srcs + N_EDGES);  // E
    float* dinv   = norms + N_EDGES;           // N
    size_t off = (size_t)(dinv + N_NODES - ws);
    off = (off + 3) & ~(size_t)3;              // 16B align
    float* hA = ws + off;                      // N*128 fp32
    unsigned* hB = (unsigned*)(hA + (size_t)N_NODES * 128);  // N*64 packed bf16 pairs

    hipMemsetAsync(d_ws, 0, zero_floats * sizeof(float), stream);
    count_deg_kernel<<<(N_EDGES + 255) / 256, 256, 0, stream>>>(ei, ew, counts, deg);
    dinv_kernel<<<(N_NODES + 255) / 256, 256, 0, stream>>>(deg, dinv);
    blocksum_kernel<<<NB, 256, 0, stream>>>(counts, bsums);
    scan_bsums_kernel<<<1, 256, 0, stream>>>(bsums, boffs, rowptr);
    rowptr_kernel<<<NB, 256, 0, stream>>>(counts, boffs, rowptr, cursor);
    fill_kernel<<<(N_EDGES + 255) / 256, 256, 0, stream>>>(ei, ew, dinv, cursor, srcs, norms);

    dim3 gN(2, (N_NODES + 63) / 64);
    // pre FC: hA = x @ pre_W + pre_b, stats0 (fp32 out)
    gemm128<false, true, true, false><<<gN, 256, 0, stream>>>(x, N_NODES, pre_W, pre_b, nullptr,
                                                              hA, stats + 0);
    affine_kernel<<<1, 128, 0, stream>>>(stats + 0, pre_bn_s, pre_bn_b, aff + 0,
                                         1.0f / N_NODES);
    for (int l = 0; l < LL; l++) {
        // hB = bf16(relu(bn(hA)) @ convW[l])
        gemm128<true, false, false, true><<<gN, 256, 0, stream>>>(
            hA, N_NODES, convW + l * 128 * 128, nullptr, aff + l * 256, hB, nullptr);
        // hA = scatter(hB) + convb[l], stats_{l+1}
        agg_kernel<<<AGG_BLOCKS, 256, 0, stream>>>(hB, rowptr, srcs, norms, dinv,
                                                   convb + l * 128, hA,
                                                   stats + (l + 1) * 256);
        affine_kernel<<<1, 128, 0, stream>>>(stats + (l + 1) * 256, bn_s + l * 128,
                                             bn_b + l * 128, aff + (l + 1) * 256,
                                             1.0f / N_NODES);
    }
    // mean pool of relu(bn(hA))
    pool_kernel<<<(N_NODES + 255) / 256, 256, 0, stream>>>(hA, aff + 4 * 256, batch, pooled, cnt);
    pooldiv_kernel<<<(GG * 128 + 255) / 256, 256, 0, stream>>>(pooled, cnt);
    // post FC
    dim3 gP(2, 4);
    gemm128<false, true, true, false><<<gP, 256, 0, stream>>>(pooled, GG, post_W, post_b, nullptr,
                                                              Z, stats + 5 * 256);
    affine_kernel<<<1, 128, 0, stream>>>(stats + 5 * 256, post_bn_s, post_bn_b, aff + 5 * 256,
                                         1.0f / GG);
    out_kernel<<<GG, 64, 0, stream>>>(Z, aff + 5 * 256, out_W, out_b, (float*)d_out);
}